// Round 9
// baseline (513.536 us; speedup 1.0000x reference)
//
#include <hip/hip_runtime.h>

#define BB   2048
#define SS   256
#define NTOK (BB*SS)
#define FIN  3
#define CND  4
#define EMB  4
#define HID  64
#define NC   256
#define TPB  256   // T=2 tokens/thread: block covers 512 tokens

typedef float f2 __attribute__((ext_vector_type(2)));
#define VFMA(a,b,c) __builtin_elementwise_fma(a,b,c)

static __device__ __forceinline__ f2 sp(float v) { f2 r; r.x = v; r.y = v; return r; }
static __device__ __forceinline__ f2 vrelu(f2 v) { return __builtin_elementwise_max(v, sp(0.0f)); }
static __device__ __forceinline__ unsigned short f2bf(float f) {   // RNE f32->bf16
    unsigned int u = __builtin_bit_cast(unsigned int, f);
    u = u + 0x7FFFu + ((u >> 16) & 1u);
    return (unsigned short)(u >> 16);
}
static __device__ __forceinline__ float bf2f(unsigned short u) {
    return __builtin_bit_cast(float, ((unsigned int)u) << 16);
}

// LDS layout. Encoder/VQ sections f32 (argmin-exact); decoder weights bf16
// (x_reco threshold 4.8 abs >> bf16 error ~1e-2). Float offsets:
#define OF_EW1T 0       // 512: [j][8] = w[0..6][j] + bias[j] packed, f32
#define OF_EW2  512     // 4096
#define OF_EB2  4608    // 64
#define OF_EW3  4672    // 256
#define OF_EB3  4928    // 4 (pad to 4944)
#define OF_CB   4944    // 1024
#define OF_CC   5968    // 256
// decoder bf16 region (addressed via ushort*; float-slot accounting):
#define OF_DW1T 6224    // 256 f-slots = 512 u16: [j][8] transposed bf16
#define OF_DW2H 6480    // 2048 f-slots = 4096 u16: [k][n] bf16
#define OF_DW3P 8528    // 128 f-slots = 256 u16: [j][4] bf16 (3 used)
#define OF_DB1  8656    // 64 f32
#define OF_DB2  8720    // 64 f32
#define OF_DB3  8784    // 4 f32
#define SMEM_F  8800    // 35.2 KB
#define U_DW1T  (OF_DW1T*2)
#define U_DW2H  (OF_DW2H*2)
#define U_DW3P  (OF_DW3P*2)

// Launch-bounds law (R3-R8 data): arch-VGPR cap = 256/W (unified 512-file
// split VGPR/AGPR). W=6->40, W=4->64, W=3->84, W=2->128. Live set here
// ~200 (h[64] f2 + pipeline) -> ONLY W=2 safe; W>=3 spills (R4/R7: FETCH
// balloons to 100s of MB..GBs, 2-13x regressions). Tripwire: FETCH_SIZE.
__global__ __launch_bounds__(TPB, 2) void vqvae_fused(
        const float* __restrict__ x, const float* __restrict__ mask,
        const float* __restrict__ cond,
        const float* __restrict__ ew1, const float* __restrict__ eb1,
        const float* __restrict__ ew2, const float* __restrict__ eb2,
        const float* __restrict__ ew3, const float* __restrict__ eb3,
        const float* __restrict__ cb,
        const float* __restrict__ dw1, const float* __restrict__ db1,
        const float* __restrict__ dw2, const float* __restrict__ db2,
        const float* __restrict__ dw3, const float* __restrict__ db3,
        float* __restrict__ out, float* __restrict__ ws) {
    __shared__ float smem[SMEM_F];
    unsigned short* sm16 = (unsigned short*)smem;
    const int tid = threadIdx.x;

    // ---- staging ----
    for (int idx = tid; idx < 512; idx += TPB) {        // EW1T: w + bias packed
        int j = idx >> 3, i = idx & 7;
        smem[OF_EW1T + idx] = (i < 7) ? ew1[i*HID + j] : eb1[j];
    }
    for (int i = tid; i < HID*HID; i += TPB) smem[OF_EW2+i] = ew2[i];
    for (int i = tid; i < HID;     i += TPB) smem[OF_EB2+i] = eb2[i];
    for (int i = tid; i < HID*EMB; i += TPB) smem[OF_EW3+i] = ew3[i];
    for (int i = tid; i < EMB;     i += TPB) smem[OF_EB3+i] = eb3[i];
    for (int i = tid; i < NC*EMB;  i += TPB) smem[OF_CB +i] = cb[i];
    {   // cc from GLOBAL cb; validated order
        float c0 = cb[tid*EMB+0], c1 = cb[tid*EMB+1];
        float c2 = cb[tid*EMB+2], c3 = cb[tid*EMB+3];
        smem[OF_CC+tid] = ((c0*c0 + c1*c1) + c2*c2) + c3*c3;
    }
    for (int idx = tid; idx < 512; idx += TPB) {        // DW1T bf16 [j][8]
        int j = idx >> 3, i = idx & 7;
        sm16[U_DW1T + idx] = f2bf(dw1[i*HID + j]);
    }
    for (int idx = tid; idx < HID*HID; idx += TPB) sm16[U_DW2H + idx] = f2bf(dw2[idx]);
    for (int idx = tid; idx < 256; idx += TPB) {        // DW3P bf16 [j][4]
        int j = idx >> 2, c = idx & 3;
        sm16[U_DW3P + idx] = (c < 3) ? f2bf(dw3[j*FIN + c]) : (unsigned short)0;
    }
    for (int i = tid; i < HID; i += TPB) smem[OF_DB1+i] = db1[i];
    for (int i = tid; i < HID; i += TPB) smem[OF_DB2+i] = db2[i];
    for (int i = tid; i < FIN; i += TPB) smem[OF_DB3+i] = db3[i];
    __syncthreads();

    // two tokens per thread; per-half math = validated scalar trees.
    const int n0 = blockIdx.x * (2*TPB) + tid;
    const int n1 = n0 + TPB;
    f2 m; m.x = mask[n0]; m.y = mask[n1];
    const int bu0 = n0 >> 8;
    const int bu1 = bu0 + 1;

    f2 xin[FIN+CND];
    #pragma unroll
    for (int i = 0; i < FIN; i++) { xin[i].x = x[n0*FIN + i] * m.x; xin[i].y = x[n1*FIN + i] * m.y; }
    #pragma unroll
    for (int i = 0; i < CND; i++) { xin[FIN+i].x = cond[bu0*CND + i] * m.x; xin[FIN+i].y = cond[bu1*CND + i] * m.y; }

    // ---- encoder L1: 7 -> 64, relu (validated i-ascending chain; reads
    // vectorized via EW1T, arithmetic tree unchanged) ----
    f2 h[HID];
    #pragma unroll
    for (int j = 0; j < HID; j++) {
        float4 wa = *(const float4*)&smem[OF_EW1T + j*8];
        float4 wb = *(const float4*)&smem[OF_EW1T + j*8 + 4];
        f2 a = xin[0] * sp(wa.x);
        a = VFMA(xin[1], sp(wa.y), a);
        a = VFMA(xin[2], sp(wa.z), a);
        a = VFMA(xin[3], sp(wa.w), a);
        a = VFMA(xin[4], sp(wb.x), a);
        a = VFMA(xin[5], sp(wb.y), a);
        a = VFMA(xin[6], sp(wb.z), a);
        h[j] = vrelu(a + sp(wb.w));
    }

    // ---- encoder L2 (relu) fused with L3 fold (validated trees, f32) ----
    f2 z0 = sp(0.f), z1 = sp(0.f), z2 = sp(0.f), z3 = sp(0.f);
    for (int jt = 0; jt < 16; jt++) {
        f2 a0 = sp(0.f), a1 = sp(0.f), a2 = sp(0.f), a3 = sp(0.f);
        #pragma unroll
        for (int k = 0; k < HID; k++) {
            float4 w = *(const float4*)&smem[OF_EW2 + k*HID + jt*4];
            a0 = VFMA(h[k], sp(w.x), a0);
            a1 = VFMA(h[k], sp(w.y), a1);
            a2 = VFMA(h[k], sp(w.z), a2);
            a3 = VFMA(h[k], sp(w.w), a3);
        }
        float4 bb = *(const float4*)&smem[OF_EB2 + jt*4];
        f2 t0 = vrelu(a0 + sp(bb.x));
        f2 t1 = vrelu(a1 + sp(bb.y));
        f2 t2 = vrelu(a2 + sp(bb.z));
        f2 t3 = vrelu(a3 + sp(bb.w));
        float4 w0 = *(const float4*)&smem[OF_EW3 + (jt*4+0)*EMB];
        z0 = VFMA(t0, sp(w0.x), z0); z1 = VFMA(t0, sp(w0.y), z1);
        z2 = VFMA(t0, sp(w0.z), z2); z3 = VFMA(t0, sp(w0.w), z3);
        float4 w1 = *(const float4*)&smem[OF_EW3 + (jt*4+1)*EMB];
        z0 = VFMA(t1, sp(w1.x), z0); z1 = VFMA(t1, sp(w1.y), z1);
        z2 = VFMA(t1, sp(w1.z), z2); z3 = VFMA(t1, sp(w1.w), z3);
        float4 w2 = *(const float4*)&smem[OF_EW3 + (jt*4+2)*EMB];
        z0 = VFMA(t2, sp(w2.x), z0); z1 = VFMA(t2, sp(w2.y), z1);
        z2 = VFMA(t2, sp(w2.z), z2); z3 = VFMA(t2, sp(w2.w), z3);
        float4 w3 = *(const float4*)&smem[OF_EW3 + (jt*4+3)*EMB];
        z0 = VFMA(t3, sp(w3.x), z0); z1 = VFMA(t3, sp(w3.y), z1);
        z2 = VFMA(t3, sp(w3.z), z2); z3 = VFMA(t3, sp(w3.w), z3);
    }
    z0 = z0 + sp(smem[OF_EB3+0]); z1 = z1 + sp(smem[OF_EB3+1]);
    z2 = z2 + sp(smem[OF_EB3+2]); z3 = z3 + sp(smem[OF_EB3+3]);

    // ---- VQ argmin: scalar, textually identical to validated version ----
    const float A0 = z0.x, A1 = z1.x, A2 = z2.x, A3 = z3.x;
    const float B0 = z0.y, B1 = z1.y, B2 = z2.y, B3 = z3.y;
    const float zzA = ((A0*A0 + A1*A1) + A2*A2) + A3*A3;
    const float zzB = ((B0*B0 + B1*B1) + B2*B2) + B3*B3;
    float bestA = 3.4e38f, bestB = 3.4e38f;
    int   biA = 0, biB = 0;
    #pragma unroll 4
    for (int ci = 0; ci < NC; ci++) {
        float4 c = *(const float4*)&smem[OF_CB + ci*EMB];
        float cc = smem[OF_CC + ci];
        float dotA = A0 * c.x;
        dotA = fmaf(A1, c.y, dotA);
        dotA = fmaf(A2, c.z, dotA);
        dotA = fmaf(A3, c.w, dotA);
        float dA = (zzA - 2.0f*dotA) + cc;
        if (dA < bestA) { bestA = dA; biA = ci; }   // strict <: np first-min
        float dotB = B0 * c.x;
        dotB = fmaf(B1, c.y, dotB);
        dotB = fmaf(B2, c.z, dotB);
        dotB = fmaf(B3, c.w, dotB);
        float dB = (zzB - 2.0f*dotB) + cc;
        if (dB < bestB) { bestB = dB; biB = ci; }
    }
    float4 qA = *(const float4*)&smem[OF_CB + biA*EMB];
    float4 qB = *(const float4*)&smem[OF_CB + biB*EMB];

    // ---- vq loss partial ----
    float e0 = A0-qA.x, e1 = A1-qA.y, e2 = A2-qA.z, e3 = A3-qA.w;
    float f0 = B0-qB.x, f1 = B1-qB.y, f2_ = B2-qB.z, f3 = B3-qB.w;
    float sq = (((e0*e0 + e1*e1) + e2*e2) + e3*e3)
             + (((f0*f0 + f1*f1) + f2_*f2_) + f3*f3);
    #pragma unroll
    for (int off = 32; off > 0; off >>= 1) sq += __shfl_down(sq, off, 64);
    if ((tid & 63) == 0) atomicAdd(ws, sq);

    out[NTOK*FIN + 1 + n0] = (float)biA;
    out[NTOK*FIN + 1 + n1] = (float)biB;

    // ---- decoder input ----
    f2 zd[EMB+CND];
    zd[0].x = qA.x*m.x; zd[0].y = qB.x*m.y;
    zd[1].x = qA.y*m.x; zd[1].y = qB.y*m.y;
    zd[2].x = qA.z*m.x; zd[2].y = qB.z*m.y;
    zd[3].x = qA.w*m.x; zd[3].y = qB.w*m.y;
    #pragma unroll
    for (int i = 0; i < CND; i++) { zd[EMB+i].x = cond[bu0*CND + i] * m.x; zd[EMB+i].y = cond[bu1*CND + i] * m.y; }

    // ---- decoder L1: 8 -> 64, relu (bf16 weights; i-ascending chain) ----
    #pragma unroll
    for (int j = 0; j < HID; j++) {
        ushort4 wa = *(const ushort4*)&sm16[U_DW1T + j*8];
        ushort4 wb = *(const ushort4*)&sm16[U_DW1T + j*8 + 4];
        f2 a = zd[0] * sp(bf2f(wa.x));
        a = VFMA(zd[1], sp(bf2f(wa.y)), a);
        a = VFMA(zd[2], sp(bf2f(wa.z)), a);
        a = VFMA(zd[3], sp(bf2f(wa.w)), a);
        a = VFMA(zd[4], sp(bf2f(wb.x)), a);
        a = VFMA(zd[5], sp(bf2f(wb.y)), a);
        a = VFMA(zd[6], sp(bf2f(wb.z)), a);
        a = VFMA(zd[7], sp(bf2f(wb.w)), a);
        h[j] = vrelu(a + sp(smem[OF_DB1 + j]));
    }

    // ---- decoder L2 (relu) fused with L3 (bf16 weights, b64 reads) ----
    f2 r0 = sp(0.f), r1 = sp(0.f), r2 = sp(0.f);
    for (int jt = 0; jt < 16; jt++) {
        f2 a0 = sp(0.f), a1 = sp(0.f), a2 = sp(0.f), a3 = sp(0.f);
        #pragma unroll
        for (int k = 0; k < HID; k++) {
            ushort4 w = *(const ushort4*)&sm16[U_DW2H + k*HID + jt*4];
            a0 = VFMA(h[k], sp(bf2f(w.x)), a0);
            a1 = VFMA(h[k], sp(bf2f(w.y)), a1);
            a2 = VFMA(h[k], sp(bf2f(w.z)), a2);
            a3 = VFMA(h[k], sp(bf2f(w.w)), a3);
        }
        float4 bb = *(const float4*)&smem[OF_DB2 + jt*4];
        f2 t0 = vrelu(a0 + sp(bb.x));
        f2 t1 = vrelu(a1 + sp(bb.y));
        f2 t2 = vrelu(a2 + sp(bb.z));
        f2 t3 = vrelu(a3 + sp(bb.w));
        #pragma unroll
        for (int jj = 0; jj < 4; jj++) {
            f2 t = (jj==0)?t0:(jj==1)?t1:(jj==2)?t2:t3;
            int j = jt*4 + jj;
            ushort4 w3 = *(const ushort4*)&sm16[U_DW3P + j*4];
            r0 = VFMA(t, sp(bf2f(w3.x)), r0);
            r1 = VFMA(t, sp(bf2f(w3.y)), r1);
            r2 = VFMA(t, sp(bf2f(w3.z)), r2);
        }
    }
    r0 = r0 + sp(smem[OF_DB3+0]);
    r1 = r1 + sp(smem[OF_DB3+1]);
    r2 = r2 + sp(smem[OF_DB3+2]);

    out[n0*FIN + 0] = r0.x;
    out[n0*FIN + 1] = r1.x;
    out[n0*FIN + 2] = r2.x;
    out[n1*FIN + 0] = r0.y;
    out[n1*FIN + 1] = r1.y;
    out[n1*FIN + 2] = r2.y;

    // ---- fused finalize: last block writes vq_loss (pattern proven R8) ----
    __syncthreads();
    if (tid == 0) {
        __threadfence();
        unsigned int old = atomicAdd((unsigned int*)(ws + 1), 1u);
        if (old == gridDim.x - 1) {
            __threadfence();
            float total = atomicAdd(ws, 0.0f);
            out[NTOK*FIN] = 1.25f * total * (1.0f / (float)(NTOK*EMB));
        }
    }
}

extern "C" void kernel_launch(void* const* d_in, const int* in_sizes, int n_in,
                              void* d_out, int out_size, void* d_ws, size_t ws_size,
                              hipStream_t stream) {
    (void)in_sizes; (void)n_in; (void)ws_size; (void)out_size;
    float* ws = (float*)d_ws;
    hipMemsetAsync(ws, 0, 2*sizeof(float), stream);  // loss accum + done counter

    vqvae_fused<<<NTOK/(2*TPB), TPB, 0, stream>>>(
        (const float*)d_in[0], (const float*)d_in[1], (const float*)d_in[2],
        (const float*)d_in[3], (const float*)d_in[4], (const float*)d_in[5],
        (const float*)d_in[6], (const float*)d_in[7], (const float*)d_in[8],
        (const float*)d_in[9], (const float*)d_in[10], (const float*)d_in[11],
        (const float*)d_in[12], (const float*)d_in[13], (const float*)d_in[14],
        (const float*)d_in[15],
        (float*)d_out, ws);
}

// Round 10
// 275.907 us; speedup vs baseline: 1.8613x; 1.8613x over previous
//
#include <hip/hip_runtime.h>

#define BB   2048
#define SS   256
#define NTOK (BB*SS)
#define FIN  3
#define CND  4
#define EMB  4
#define HID  64
#define NC   256
#define TPB  256   // T=2 tokens/thread: block covers 512 tokens

typedef float f2 __attribute__((ext_vector_type(2)));
#define VFMA(a,b,c) __builtin_elementwise_fma(a,b,c)

static __device__ __forceinline__ f2 sp(float v) { f2 r; r.x = v; r.y = v; return r; }
static __device__ __forceinline__ f2 vrelu(f2 v) { return __builtin_elementwise_max(v, sp(0.0f)); }

// LDS: only small weights + VQ tables. The two 16 KB matrices (EW2, DW2) are
// read straight from GLOBAL with wave-uniform indices -> scalar s_load path
// (off the oversubscribed LDS pipe; R6's 211 us is LDS-pipe-bound).
// All f32 (R9's bf16 unpack caused spill: per-element cvt temporaries).
#define OF_EW1T 0       // 512: [j][8] = ew1[0..6][j] + eb1[j], f32
#define OF_EW3  512     // 256
#define OF_EB3  768     // 4 (pad to 784)
#define OF_CB   784     // 1024 (784*4 % 16 == 0)
#define OF_CC   1808    // 256
#define OF_DW1T 2064    // 512: [j][8] = dw1[0..7][j]
#define OF_DB1  2576    // 64
#define OF_DB2  2640    // 64
#define OF_DW3  2704    // 192
#define OF_DB3  2896    // 3 (pad to 2900)
#define OF_EB2  2900    // 64 (2900*4 % 16 == 0)
#define SMEM_F  2964    // 11.9 KB

// Launch-bounds law (R3-R9): arch-VGPR cap = 256/W. W=6->40, W=4->64,
// W=3->84, W=2->128. Live set here ~250 (h[64] f2 + pipeline) -> ONLY W=2.
// Also: R6's loop bodies sit exactly at the budget; adding ANY per-element
// VALU work in hot loops (R9 bf16 unpack) spills. Tripwire: FETCH_SIZE.
__global__ __launch_bounds__(TPB, 2) void vqvae_fused(
        const float* __restrict__ x, const float* __restrict__ mask,
        const float* __restrict__ cond,
        const float* __restrict__ ew1, const float* __restrict__ eb1,
        const float* __restrict__ ew2, const float* __restrict__ eb2,
        const float* __restrict__ ew3, const float* __restrict__ eb3,
        const float* __restrict__ cb,
        const float* __restrict__ dw1, const float* __restrict__ db1,
        const float* __restrict__ dw2, const float* __restrict__ db2,
        const float* __restrict__ dw3, const float* __restrict__ db3,
        float* __restrict__ out, float* __restrict__ ws) {
    __shared__ float smem[SMEM_F];
    const int tid = threadIdx.x;

    // ---- staging (small tables only) ----
    for (int idx = tid; idx < 512; idx += TPB) {        // EW1T: w + bias packed
        int j = idx >> 3, i = idx & 7;
        smem[OF_EW1T + idx] = (i < 7) ? ew1[i*HID + j] : eb1[j];
    }
    for (int i = tid; i < HID*EMB; i += TPB) smem[OF_EW3+i] = ew3[i];
    for (int i = tid; i < EMB;     i += TPB) smem[OF_EB3+i] = eb3[i];
    for (int i = tid; i < NC*EMB;  i += TPB) smem[OF_CB +i] = cb[i];
    {   // cc from GLOBAL cb; validated order
        float c0 = cb[tid*EMB+0], c1 = cb[tid*EMB+1];
        float c2 = cb[tid*EMB+2], c3 = cb[tid*EMB+3];
        smem[OF_CC+tid] = ((c0*c0 + c1*c1) + c2*c2) + c3*c3;
    }
    for (int idx = tid; idx < 512; idx += TPB) {        // DW1T f32 [j][8]
        int j = idx >> 3, i = idx & 7;
        smem[OF_DW1T + idx] = dw1[i*HID + j];
    }
    for (int i = tid; i < HID;     i += TPB) smem[OF_DB1+i] = db1[i];
    for (int i = tid; i < HID;     i += TPB) smem[OF_DB2+i] = db2[i];
    for (int i = tid; i < HID*FIN; i += TPB) smem[OF_DW3+i] = dw3[i];
    for (int i = tid; i < FIN;     i += TPB) smem[OF_DB3+i] = db3[i];
    for (int i = tid; i < HID;     i += TPB) smem[OF_EB2+i] = eb2[i];
    __syncthreads();

    // two tokens per thread; per-half math = validated scalar trees.
    const int n0 = blockIdx.x * (2*TPB) + tid;
    const int n1 = n0 + TPB;
    f2 m; m.x = mask[n0]; m.y = mask[n1];
    const int bu0 = n0 >> 8;
    const int bu1 = bu0 + 1;

    f2 xin[FIN+CND];
    #pragma unroll
    for (int i = 0; i < FIN; i++) { xin[i].x = x[n0*FIN + i] * m.x; xin[i].y = x[n1*FIN + i] * m.y; }
    #pragma unroll
    for (int i = 0; i < CND; i++) { xin[FIN+i].x = cond[bu0*CND + i] * m.x; xin[FIN+i].y = cond[bu1*CND + i] * m.y; }

    // ---- encoder L1: 7 -> 64, relu (validated i-ascending chain; packed
    // vector reads, arithmetic tree unchanged — form validated in R9) ----
    f2 h[HID];
    #pragma unroll
    for (int j = 0; j < HID; j++) {
        float4 wa = *(const float4*)&smem[OF_EW1T + j*8];
        float4 wb = *(const float4*)&smem[OF_EW1T + j*8 + 4];
        f2 a = xin[0] * sp(wa.x);
        a = VFMA(xin[1], sp(wa.y), a);
        a = VFMA(xin[2], sp(wa.z), a);
        a = VFMA(xin[3], sp(wa.w), a);
        a = VFMA(xin[4], sp(wb.x), a);
        a = VFMA(xin[5], sp(wb.y), a);
        a = VFMA(xin[6], sp(wb.z), a);
        h[j] = vrelu(a + sp(wb.w));
    }

    // ---- encoder L2 (relu) fused with L3 fold (validated trees, f32).
    // EW2 read from GLOBAL with uniform index -> scalar s_load path. ----
    f2 z0 = sp(0.f), z1 = sp(0.f), z2 = sp(0.f), z3 = sp(0.f);
    for (int jt = 0; jt < 16; jt++) {
        f2 a0 = sp(0.f), a1 = sp(0.f), a2 = sp(0.f), a3 = sp(0.f);
        #pragma unroll
        for (int k = 0; k < HID; k++) {
            float4 w = *(const float4*)&ew2[k*HID + jt*4];   // wave-uniform
            a0 = VFMA(h[k], sp(w.x), a0);
            a1 = VFMA(h[k], sp(w.y), a1);
            a2 = VFMA(h[k], sp(w.z), a2);
            a3 = VFMA(h[k], sp(w.w), a3);
        }
        float4 bb = *(const float4*)&smem[OF_EB2 + jt*4];
        f2 t0 = vrelu(a0 + sp(bb.x));
        f2 t1 = vrelu(a1 + sp(bb.y));
        f2 t2 = vrelu(a2 + sp(bb.z));
        f2 t3 = vrelu(a3 + sp(bb.w));
        float4 w0 = *(const float4*)&smem[OF_EW3 + (jt*4+0)*EMB];
        z0 = VFMA(t0, sp(w0.x), z0); z1 = VFMA(t0, sp(w0.y), z1);
        z2 = VFMA(t0, sp(w0.z), z2); z3 = VFMA(t0, sp(w0.w), z3);
        float4 w1 = *(const float4*)&smem[OF_EW3 + (jt*4+1)*EMB];
        z0 = VFMA(t1, sp(w1.x), z0); z1 = VFMA(t1, sp(w1.y), z1);
        z2 = VFMA(t1, sp(w1.z), z2); z3 = VFMA(t1, sp(w1.w), z3);
        float4 w2 = *(const float4*)&smem[OF_EW3 + (jt*4+2)*EMB];
        z0 = VFMA(t2, sp(w2.x), z0); z1 = VFMA(t2, sp(w2.y), z1);
        z2 = VFMA(t2, sp(w2.z), z2); z3 = VFMA(t2, sp(w2.w), z3);
        float4 w3 = *(const float4*)&smem[OF_EW3 + (jt*4+3)*EMB];
        z0 = VFMA(t3, sp(w3.x), z0); z1 = VFMA(t3, sp(w3.y), z1);
        z2 = VFMA(t3, sp(w3.z), z2); z3 = VFMA(t3, sp(w3.w), z3);
    }
    z0 = z0 + sp(smem[OF_EB3+0]); z1 = z1 + sp(smem[OF_EB3+1]);
    z2 = z2 + sp(smem[OF_EB3+2]); z3 = z3 + sp(smem[OF_EB3+3]);

    // ---- VQ argmin: scalar, textually identical to validated version ----
    const float A0 = z0.x, A1 = z1.x, A2 = z2.x, A3 = z3.x;
    const float B0 = z0.y, B1 = z1.y, B2 = z2.y, B3 = z3.y;
    const float zzA = ((A0*A0 + A1*A1) + A2*A2) + A3*A3;
    const float zzB = ((B0*B0 + B1*B1) + B2*B2) + B3*B3;
    float bestA = 3.4e38f, bestB = 3.4e38f;
    int   biA = 0, biB = 0;
    #pragma unroll 4
    for (int ci = 0; ci < NC; ci++) {
        float4 c = *(const float4*)&smem[OF_CB + ci*EMB];
        float cc = smem[OF_CC + ci];
        float dotA = A0 * c.x;
        dotA = fmaf(A1, c.y, dotA);
        dotA = fmaf(A2, c.z, dotA);
        dotA = fmaf(A3, c.w, dotA);
        float dA = (zzA - 2.0f*dotA) + cc;
        if (dA < bestA) { bestA = dA; biA = ci; }   // strict <: np first-min
        float dotB = B0 * c.x;
        dotB = fmaf(B1, c.y, dotB);
        dotB = fmaf(B2, c.z, dotB);
        dotB = fmaf(B3, c.w, dotB);
        float dB = (zzB - 2.0f*dotB) + cc;
        if (dB < bestB) { bestB = dB; biB = ci; }
    }
    float4 qA = *(const float4*)&smem[OF_CB + biA*EMB];
    float4 qB = *(const float4*)&smem[OF_CB + biB*EMB];

    // ---- vq loss partial ----
    float e0 = A0-qA.x, e1 = A1-qA.y, e2 = A2-qA.z, e3 = A3-qA.w;
    float f0 = B0-qB.x, f1 = B1-qB.y, f2_ = B2-qB.z, f3 = B3-qB.w;
    float sq = (((e0*e0 + e1*e1) + e2*e2) + e3*e3)
             + (((f0*f0 + f1*f1) + f2_*f2_) + f3*f3);
    #pragma unroll
    for (int off = 32; off > 0; off >>= 1) sq += __shfl_down(sq, off, 64);
    if ((tid & 63) == 0) atomicAdd(ws, sq);

    out[NTOK*FIN + 1 + n0] = (float)biA;
    out[NTOK*FIN + 1 + n1] = (float)biB;

    // ---- decoder input ----
    f2 zd[EMB+CND];
    zd[0].x = qA.x*m.x; zd[0].y = qB.x*m.y;
    zd[1].x = qA.y*m.x; zd[1].y = qB.y*m.y;
    zd[2].x = qA.z*m.x; zd[2].y = qB.z*m.y;
    zd[3].x = qA.w*m.x; zd[3].y = qB.w*m.y;
    #pragma unroll
    for (int i = 0; i < CND; i++) { zd[EMB+i].x = cond[bu0*CND + i] * m.x; zd[EMB+i].y = cond[bu1*CND + i] * m.y; }

    // ---- decoder L1: 8 -> 64, relu (f32 packed, validated chain) ----
    #pragma unroll
    for (int j = 0; j < HID; j++) {
        float4 wa = *(const float4*)&smem[OF_DW1T + j*8];
        float4 wb = *(const float4*)&smem[OF_DW1T + j*8 + 4];
        f2 a = zd[0] * sp(wa.x);
        a = VFMA(zd[1], sp(wa.y), a);
        a = VFMA(zd[2], sp(wa.z), a);
        a = VFMA(zd[3], sp(wa.w), a);
        a = VFMA(zd[4], sp(wb.x), a);
        a = VFMA(zd[5], sp(wb.y), a);
        a = VFMA(zd[6], sp(wb.z), a);
        a = VFMA(zd[7], sp(wb.w), a);
        h[j] = vrelu(a + sp(smem[OF_DB1 + j]));
    }

    // ---- decoder L2 (relu) fused with L3. DW2 from GLOBAL (uniform). ----
    f2 r0 = sp(0.f), r1 = sp(0.f), r2 = sp(0.f);
    for (int jt = 0; jt < 16; jt++) {
        f2 a0 = sp(0.f), a1 = sp(0.f), a2 = sp(0.f), a3 = sp(0.f);
        #pragma unroll
        for (int k = 0; k < HID; k++) {
            float4 w = *(const float4*)&dw2[k*HID + jt*4];   // wave-uniform
            a0 = VFMA(h[k], sp(w.x), a0);
            a1 = VFMA(h[k], sp(w.y), a1);
            a2 = VFMA(h[k], sp(w.z), a2);
            a3 = VFMA(h[k], sp(w.w), a3);
        }
        float4 bb = *(const float4*)&smem[OF_DB2 + jt*4];
        f2 t0 = vrelu(a0 + sp(bb.x));
        f2 t1 = vrelu(a1 + sp(bb.y));
        f2 t2 = vrelu(a2 + sp(bb.z));
        f2 t3 = vrelu(a3 + sp(bb.w));
        #pragma unroll
        for (int jj = 0; jj < 4; jj++) {
            f2 t = (jj==0)?t0:(jj==1)?t1:(jj==2)?t2:t3;
            int j = jt*4 + jj;
            r0 = VFMA(t, sp(smem[OF_DW3 + j*FIN + 0]), r0);
            r1 = VFMA(t, sp(smem[OF_DW3 + j*FIN + 1]), r1);
            r2 = VFMA(t, sp(smem[OF_DW3 + j*FIN + 2]), r2);
        }
    }
    r0 = r0 + sp(smem[OF_DB3+0]);
    r1 = r1 + sp(smem[OF_DB3+1]);
    r2 = r2 + sp(smem[OF_DB3+2]);

    out[n0*FIN + 0] = r0.x;
    out[n0*FIN + 1] = r1.x;
    out[n0*FIN + 2] = r2.x;
    out[n1*FIN + 0] = r0.y;
    out[n1*FIN + 1] = r1.y;
    out[n1*FIN + 2] = r2.y;

    // ---- fused finalize: last block writes vq_loss (pattern proven R8) ----
    __syncthreads();
    if (tid == 0) {
        __threadfence();
        unsigned int old = atomicAdd((unsigned int*)(ws + 1), 1u);
        if (old == gridDim.x - 1) {
            __threadfence();
            float total = atomicAdd(ws, 0.0f);
            out[NTOK*FIN] = 1.25f * total * (1.0f / (float)(NTOK*EMB));
        }
    }
}

extern "C" void kernel_launch(void* const* d_in, const int* in_sizes, int n_in,
                              void* d_out, int out_size, void* d_ws, size_t ws_size,
                              hipStream_t stream) {
    (void)in_sizes; (void)n_in; (void)ws_size; (void)out_size;
    float* ws = (float*)d_ws;
    hipMemsetAsync(ws, 0, 2*sizeof(float), stream);  // loss accum + done counter

    vqvae_fused<<<NTOK/(2*TPB), TPB, 0, stream>>>(
        (const float*)d_in[0], (const float*)d_in[1], (const float*)d_in[2],
        (const float*)d_in[3], (const float*)d_in[4], (const float*)d_in[5],
        (const float*)d_in[6], (const float*)d_in[7], (const float*)d_in[8],
        (const float*)d_in[9], (const float*)d_in[10], (const float*)d_in[11],
        (const float*)d_in[12], (const float*)d_in[13], (const float*)d_in[14],
        (const float*)d_in[15],
        (float*)d_out, ws);
}